// Round 4
// baseline (417.525 us; speedup 1.0000x reference)
//
#include <hip/hip_runtime.h>

#define HH_EPS 1e-6f

// ws layout (floats):
//   [0,256)              G  (16x16 Gram)
//   [256,512)            T  (16x16 row-major)
//   [512, 512+131072)    yacc (8192 x 16)  -- atomically accumulated y = V.x
//   [512+131072, +131072) wbuf (8192 x 16) -- w = T.y per row
#define WS_YACC 512
#define WS_WBUF (512 + 131072)

// ---------------------------------------------------------------------------
// K0: zero the y accumulator (ws is poisoned 0xAA before every call).
// ---------------------------------------------------------------------------
__global__ __launch_bounds__(256) void hh_zero_y(float* __restrict__ ws) {
    ws[WS_YACC + blockIdx.x * 256 + threadIdx.x] = 0.f;
}

// ---------------------------------------------------------------------------
// K1: Gram matrix. 136 blocks, one per pair (k,i), i<=k. Shuffle reduce.
// ---------------------------------------------------------------------------
__global__ __launch_bounds__(256) void hh_gram(const float* __restrict__ V,
                                               float* __restrict__ ws) {
    int b = blockIdx.x;
    int k = 0;
    while (b >= k + 1) { b -= k + 1; ++k; }
    const int i = b;

    const float4* V4 = (const float4*)V;
    const int t = threadIdx.x;
    const int wave = t >> 6;
    const int lane = t & 63;

    float acc = 0.f;
    #pragma unroll
    for (int c = 0; c < 4; ++c) {
        const float4 a = V4[k * 1024 + t + 256 * c];
        const float4 v = V4[i * 1024 + t + 256 * c];
        acc = fmaf(a.x, v.x, acc);
        acc = fmaf(a.y, v.y, acc);
        acc = fmaf(a.z, v.z, acc);
        acc = fmaf(a.w, v.w, acc);
    }
    #pragma unroll
    for (int off = 32; off >= 1; off >>= 1)
        acc += __shfl_xor(acc, off, 64);

    __shared__ float red[4];
    if (lane == 0) red[wave] = acc;
    __syncthreads();
    if (t == 0) {
        const float g = red[0] + red[1] + red[2] + red[3];
        ws[k * 16 + i] = g;
        ws[i * 16 + k] = g;
    }
}

// ---------------------------------------------------------------------------
// K2: T factor. One wave; lane j owns column T[.][j] in registers.
// ---------------------------------------------------------------------------
__global__ __launch_bounds__(64) void hh_T(float* __restrict__ ws) {
    __shared__ float Gs[256];
    const int t = threadIdx.x;
    #pragma unroll
    for (int q = 0; q < 4; ++q) Gs[t * 4 + q] = ws[t * 4 + q];
    __syncthreads();

    const int j = t;
    float tc[16];
    #pragma unroll
    for (int k = 0; k < 16; ++k) {
        const float beta = 2.0f / (Gs[k * 16 + k] + HH_EPS);
        float s = 0.f;
        #pragma unroll
        for (int i = 0; i < k; ++i) {
            const float g = Gs[k * 16 + i];
            s = fmaf((i >= j) ? g : 0.f, tc[i], s);
        }
        tc[k] = (j == k) ? beta : ((j < k) ? (-beta * s) : 0.f);
    }
    if (j < 16) {
        #pragma unroll
        for (int i = 0; i < 16; ++i) ws[256 + i * 16 + j] = tc[i];
    }
}

// ---------------------------------------------------------------------------
// K3 (pass 1): y[row][j] += X[row][cols] . V[j][cols]  -- lane owns a ROW.
// No cross-lane reduction, no barriers. Grid = 32 row-groups x 16 col-splits.
// Each lane: 16 f32 accumulators; reads its row as 4 consecutive float4 per
// step (one full 128B line per lane). V reads are wave-uniform (scalarized).
// ---------------------------------------------------------------------------
__global__ __launch_bounds__(256) void hh_project(const float* __restrict__ X,
                                                  const float* __restrict__ V,
                                                  float* __restrict__ ws) {
    const int rg = blockIdx.x >> 4;    // row group, 256 rows
    const int cs = blockIdx.x & 15;    // col split, 256 cols (64 float4)
    const int wave = threadIdx.x >> 6;
    const int lane = threadIdx.x & 63;
    const int row = rg * 256 + wave * 64 + lane;

    const float4* X4 = (const float4*)X + (size_t)row * 1024 + cs * 64;
    const float4* V4 = (const float4*)V + cs * 64;

    float acc[16];
    #pragma unroll
    for (int j = 0; j < 16; ++j) acc[j] = 0.f;

    for (int it = 0; it < 16; ++it) {
        float4 xq[4];
        #pragma unroll
        for (int q = 0; q < 4; ++q) xq[q] = X4[it * 4 + q];
        #pragma unroll
        for (int q = 0; q < 4; ++q) {
            #pragma unroll
            for (int j = 0; j < 16; ++j) {
                const float4 v = V4[j * 1024 + it * 4 + q];
                float s = acc[j];
                s = fmaf(xq[q].x, v.x, s);
                s = fmaf(xq[q].y, v.y, s);
                s = fmaf(xq[q].z, v.z, s);
                s = fmaf(xq[q].w, v.w, s);
                acc[j] = s;
            }
        }
    }

    float* yacc = ws + WS_YACC + (size_t)row * 16;
    #pragma unroll
    for (int j = 0; j < 16; ++j) atomicAdd(&yacc[j], acc[j]);
}

// ---------------------------------------------------------------------------
// K4: per-row w = T . y. 32 blocks x 256 threads, one row per thread.
// ---------------------------------------------------------------------------
__global__ __launch_bounds__(256) void hh_wvec(float* __restrict__ ws) {
    __shared__ float Ts[256];
    Ts[threadIdx.x] = ws[256 + threadIdx.x];
    __syncthreads();

    const int r = blockIdx.x * 256 + threadIdx.x;
    const float4* y4 = (const float4*)(ws + WS_YACC) + (size_t)r * 4;
    float y[16];
    #pragma unroll
    for (int q = 0; q < 4; ++q) {
        const float4 v = y4[q];
        y[q * 4 + 0] = v.x; y[q * 4 + 1] = v.y;
        y[q * 4 + 2] = v.z; y[q * 4 + 3] = v.w;
    }
    float4* w4 = (float4*)(ws + WS_WBUF) + (size_t)r * 4;
    #pragma unroll
    for (int q = 0; q < 4; ++q) {
        float4 o;
        float* op = (float*)&o;
        #pragma unroll
        for (int kk = 0; kk < 4; ++kk) {
            const int k = q * 4 + kk;
            float s = 0.f;
            #pragma unroll
            for (int j = 0; j < 16; ++j) s = fmaf(Ts[k * 16 + j], y[j], s);
            op[kk] = s;
        }
        w4[q] = o;
    }
}

// ---------------------------------------------------------------------------
// K5 (pass 2): out = X - w^T V. Pure stream, 4 rows/block, no reductions.
// ---------------------------------------------------------------------------
__global__ __launch_bounds__(256) void hh_update(const float* __restrict__ X,
                                                 const float* __restrict__ V,
                                                 const float* __restrict__ ws,
                                                 float* __restrict__ Out) {
    const float4* X4 = (const float4*)X;
    const float4* V4 = (const float4*)V;
    float4* O4 = (float4*)Out;

    const int t = threadIdx.x;
    const int rb = blockIdx.x * 4;

    __shared__ float wf[4][16];
    if (t < 64) wf[t >> 4][t & 15] = ws[WS_WBUF + rb * 16 + t];

    float4 xr[4][4];
    #pragma unroll
    for (int r = 0; r < 4; ++r)
        #pragma unroll
        for (int c = 0; c < 4; ++c)
            xr[r][c] = X4[(size_t)(rb + r) * 1024 + t + 256 * c];
    __syncthreads();

    for (int j = 0; j < 16; ++j) {
        const float w0 = -wf[0][j], w1 = -wf[1][j];
        const float w2 = -wf[2][j], w3 = -wf[3][j];
        #pragma unroll
        for (int c = 0; c < 4; ++c) {
            const float4 v = V4[j * 1024 + t + 256 * c];
            xr[0][c].x = fmaf(w0, v.x, xr[0][c].x);
            xr[0][c].y = fmaf(w0, v.y, xr[0][c].y);
            xr[0][c].z = fmaf(w0, v.z, xr[0][c].z);
            xr[0][c].w = fmaf(w0, v.w, xr[0][c].w);
            xr[1][c].x = fmaf(w1, v.x, xr[1][c].x);
            xr[1][c].y = fmaf(w1, v.y, xr[1][c].y);
            xr[1][c].z = fmaf(w1, v.z, xr[1][c].z);
            xr[1][c].w = fmaf(w1, v.w, xr[1][c].w);
            xr[2][c].x = fmaf(w2, v.x, xr[2][c].x);
            xr[2][c].y = fmaf(w2, v.y, xr[2][c].y);
            xr[2][c].z = fmaf(w2, v.z, xr[2][c].z);
            xr[2][c].w = fmaf(w2, v.w, xr[2][c].w);
            xr[3][c].x = fmaf(w3, v.x, xr[3][c].x);
            xr[3][c].y = fmaf(w3, v.y, xr[3][c].y);
            xr[3][c].z = fmaf(w3, v.z, xr[3][c].z);
            xr[3][c].w = fmaf(w3, v.w, xr[3][c].w);
        }
    }

    #pragma unroll
    for (int r = 0; r < 4; ++r)
        #pragma unroll
        for (int c = 0; c < 4; ++c)
            O4[(size_t)(rb + r) * 1024 + t + 256 * c] = xr[r][c];
}

// ---------------------------------------------------------------------------
extern "C" void kernel_launch(void* const* d_in, const int* in_sizes, int n_in,
                              void* d_out, int out_size, void* d_ws, size_t ws_size,
                              hipStream_t stream) {
    const float* X = (const float*)d_in[0];   // (4,2048,4096) f32 = 8192 rows
    const float* V = (const float*)d_in[1];   // (16,4096) f32
    float* O = (float*)d_out;
    float* ws = (float*)d_ws;                 // needs 512 + 2*131072 floats ~ 1.05 MB

    hh_zero_y<<<512, 256, 0, stream>>>(ws);
    hh_gram<<<136, 256, 0, stream>>>(V, ws);
    hh_T<<<1, 64, 0, stream>>>(ws);
    hh_project<<<512, 256, 0, stream>>>(X, V, ws);
    hh_wvec<<<32, 256, 0, stream>>>(ws);
    hh_update<<<2048, 256, 0, stream>>>(X, V, ws, O);
}

// Round 5
// 405.223 us; speedup vs baseline: 1.0304x; 1.0304x over previous
//
#include <hip/hip_runtime.h>

#define HH_EPS 1e-6f

// ws layout (floats):
//   [0,256)        G  (16x16 Gram)
//   [256,512)      T  (16x16 row-major, lower-triangular)
//   [512,66048)    B2 = T^T * V  (16 x 4096 row-major)
// out = x - sum_j y_j * B2_j,  y = V . x   (per row)

// ---------------------------------------------------------------------------
// K1: Gram matrix. 136 blocks, one per pair (k,i), i<=k. Shuffle reduce.
// ---------------------------------------------------------------------------
__global__ __launch_bounds__(256) void hh_gram(const float* __restrict__ V,
                                               float* __restrict__ ws) {
    int b = blockIdx.x;
    int k = 0;
    while (b >= k + 1) { b -= k + 1; ++k; }
    const int i = b;

    const float4* V4 = (const float4*)V;
    const int t = threadIdx.x;
    const int wave = t >> 6;
    const int lane = t & 63;

    float acc = 0.f;
    #pragma unroll
    for (int c = 0; c < 4; ++c) {
        const float4 a = V4[k * 1024 + t + 256 * c];
        const float4 v = V4[i * 1024 + t + 256 * c];
        acc = fmaf(a.x, v.x, acc);
        acc = fmaf(a.y, v.y, acc);
        acc = fmaf(a.z, v.z, acc);
        acc = fmaf(a.w, v.w, acc);
    }
    #pragma unroll
    for (int off = 32; off >= 1; off >>= 1)
        acc += __shfl_xor(acc, off, 64);

    __shared__ float red[4];
    if (lane == 0) red[wave] = acc;
    __syncthreads();
    if (t == 0) {
        const float g = red[0] + red[1] + red[2] + red[3];
        ws[k * 16 + i] = g;
        ws[i * 16 + k] = g;
    }
}

// ---------------------------------------------------------------------------
// K2: T factor. One wave; lane j owns column T[.][j] in registers.
// ---------------------------------------------------------------------------
__global__ __launch_bounds__(64) void hh_T(float* __restrict__ ws) {
    __shared__ float Gs[256];
    const int t = threadIdx.x;
    #pragma unroll
    for (int q = 0; q < 4; ++q) Gs[t * 4 + q] = ws[t * 4 + q];
    __syncthreads();

    const int j = t;
    float tc[16];
    #pragma unroll
    for (int k = 0; k < 16; ++k) {
        const float beta = 2.0f / (Gs[k * 16 + k] + HH_EPS);
        float s = 0.f;
        #pragma unroll
        for (int i = 0; i < k; ++i) {
            const float g = Gs[k * 16 + i];
            s = fmaf((i >= j) ? g : 0.f, tc[i], s);
        }
        tc[k] = (j == k) ? beta : ((j < k) ? (-beta * s) : 0.f);
    }
    if (j < 16) {
        #pragma unroll
        for (int i = 0; i < 16; ++i) ws[256 + i * 16 + j] = tc[i];
    }
}

// ---------------------------------------------------------------------------
// K3: B2 = T^T V, i.e. b2_j = sum_k T[k][j] v_k.  (16 x 4096 row-major)
// 64 blocks x 256 threads; each thread one float4 of B2.
// ---------------------------------------------------------------------------
__global__ __launch_bounds__(256) void hh_B2(const float* __restrict__ V,
                                             float* __restrict__ ws) {
    const float* T = ws + 256;
    float4* B4 = (float4*)(ws + 512);
    const float4* V4 = (const float4*)V;
    const int tid = blockIdx.x * 256 + threadIdx.x;  // 0..16383
    const int j = tid >> 10;                          // B2 row 0..15
    const int d4 = tid & 1023;                        // float4 column
    float4 acc = make_float4(0.f, 0.f, 0.f, 0.f);
    for (int k = j; k < 16; ++k) {                    // T lower-tri: T[k][j]=0 for k<j
        const float tv = T[k * 16 + j];
        const float4 v = V4[k * 1024 + d4];
        acc.x = fmaf(tv, v.x, acc.x);
        acc.y = fmaf(tv, v.y, acc.y);
        acc.z = fmaf(tv, v.z, acc.z);
        acc.w = fmaf(tv, v.w, acc.w);
    }
    B4[tid] = acc;
}

// ---------------------------------------------------------------------------
// K4: fused single-pass apply. 4 rows/block, rows in registers (16 float4/thr).
// Phase 1: y[j][r] = row_r . V_j, computed in 4 batches of 4 j's:
//   16 independent depth-4 FMA chains, then ONE 6-step butterfly allreduce
//   over all 16 partials (16-wide ILP) -> 4 reduction bursts total.
// Phase 2: out_r = row_r - sum_j y[j][r] * B2_j  (B2 folds T, no w matvec).
// Two barriers total.
// ---------------------------------------------------------------------------
__global__ __launch_bounds__(256, 4) void hh_apply(const float* __restrict__ X,
                                                   const float* __restrict__ V,
                                                   const float* __restrict__ ws,
                                                   float* __restrict__ Out) {
    const float4* X4 = (const float4*)X;
    const float4* V4 = (const float4*)V;
    const float4* B24 = (const float4*)(ws + 512);
    float4* O4 = (float4*)Out;

    const int t = threadIdx.x;
    const int wave = t >> 6;
    const int lane = t & 63;
    const int rb = blockIdx.x * 4;

    __shared__ alignas(16) float pw[4][16][4];  // [wave][j][r]
    __shared__ alignas(16) float yw[16][4];     // y[j][r]

    // Load 4 rows, coalesced: thread t owns float4 cols {t, t+256, t+512, t+768}
    float4 xr[4][4];
    #pragma unroll
    for (int r = 0; r < 4; ++r)
        #pragma unroll
        for (int c = 0; c < 4; ++c)
            xr[r][c] = X4[(size_t)(rb + r) * 1024 + t + 256 * c];

    // ---- Phase 1: y = V . rows, 4 j's per batch ----
    #pragma unroll
    for (int g = 0; g < 4; ++g) {
        float acc[4][4];  // [jj][r]
        #pragma unroll
        for (int jj = 0; jj < 4; ++jj)
            #pragma unroll
            for (int r = 0; r < 4; ++r) acc[jj][r] = 0.f;

        #pragma unroll
        for (int c = 0; c < 4; ++c) {
            float4 bv[4];
            #pragma unroll
            for (int jj = 0; jj < 4; ++jj)
                bv[jj] = V4[(4 * g + jj) * 1024 + t + 256 * c];
            #pragma unroll
            for (int jj = 0; jj < 4; ++jj) {
                #pragma unroll
                for (int r = 0; r < 4; ++r) {
                    float s = acc[jj][r];
                    s = fmaf(xr[r][c].x, bv[jj].x, s);
                    s = fmaf(xr[r][c].y, bv[jj].y, s);
                    s = fmaf(xr[r][c].z, bv[jj].z, s);
                    s = fmaf(xr[r][c].w, bv[jj].w, s);
                    acc[jj][r] = s;
                }
            }
        }

        // One butterfly allreduce over all 16 partials (16-wide ILP per step)
        #pragma unroll
        for (int off = 32; off >= 1; off >>= 1) {
            #pragma unroll
            for (int jj = 0; jj < 4; ++jj)
                #pragma unroll
                for (int r = 0; r < 4; ++r)
                    acc[jj][r] += __shfl_xor(acc[jj][r], off, 64);
        }

        if (lane == 0) {
            #pragma unroll
            for (int jj = 0; jj < 4; ++jj)
                *(float4*)&pw[wave][4 * g + jj][0] =
                    make_float4(acc[jj][0], acc[jj][1], acc[jj][2], acc[jj][3]);
        }
    }
    __syncthreads();

    // Cross-wave combine: y[j][r] = sum over 4 waves
    if (t < 64) {
        const int j = t >> 2, r = t & 3;
        yw[j][r] = pw[0][j][r] + pw[1][j][r] + pw[2][j][r] + pw[3][j][r];
    }
    __syncthreads();

    // ---- Phase 2: out_r = row_r - sum_j y[j][r] * B2_j ----
    #pragma unroll 2
    for (int j = 0; j < 16; ++j) {
        const float4 y4 = *(const float4*)&yw[j][0];  // LDS broadcast
        const float n0 = -y4.x, n1 = -y4.y, n2 = -y4.z, n3 = -y4.w;
        #pragma unroll
        for (int c = 0; c < 4; ++c) {
            const float4 b = B24[j * 1024 + t + 256 * c];
            xr[0][c].x = fmaf(n0, b.x, xr[0][c].x);
            xr[0][c].y = fmaf(n0, b.y, xr[0][c].y);
            xr[0][c].z = fmaf(n0, b.z, xr[0][c].z);
            xr[0][c].w = fmaf(n0, b.w, xr[0][c].w);
            xr[1][c].x = fmaf(n1, b.x, xr[1][c].x);
            xr[1][c].y = fmaf(n1, b.y, xr[1][c].y);
            xr[1][c].z = fmaf(n1, b.z, xr[1][c].z);
            xr[1][c].w = fmaf(n1, b.w, xr[1][c].w);
            xr[2][c].x = fmaf(n2, b.x, xr[2][c].x);
            xr[2][c].y = fmaf(n2, b.y, xr[2][c].y);
            xr[2][c].z = fmaf(n2, b.z, xr[2][c].z);
            xr[2][c].w = fmaf(n2, b.w, xr[2][c].w);
            xr[3][c].x = fmaf(n3, b.x, xr[3][c].x);
            xr[3][c].y = fmaf(n3, b.y, xr[3][c].y);
            xr[3][c].z = fmaf(n3, b.z, xr[3][c].z);
            xr[3][c].w = fmaf(n3, b.w, xr[3][c].w);
        }
    }

    #pragma unroll
    for (int r = 0; r < 4; ++r)
        #pragma unroll
        for (int c = 0; c < 4; ++c)
            O4[(size_t)(rb + r) * 1024 + t + 256 * c] = xr[r][c];
}

// ---------------------------------------------------------------------------
extern "C" void kernel_launch(void* const* d_in, const int* in_sizes, int n_in,
                              void* d_out, int out_size, void* d_ws, size_t ws_size,
                              hipStream_t stream) {
    const float* X = (const float*)d_in[0];   // (4,2048,4096) f32 = 8192 rows
    const float* V = (const float*)d_in[1];   // (16,4096) f32
    float* O = (float*)d_out;
    float* ws = (float*)d_ws;                 // needs 66048 floats ~ 258 KiB

    hh_gram<<<136, 256, 0, stream>>>(V, ws);
    hh_T<<<1, 64, 0, stream>>>(ws);
    hh_B2<<<64, 256, 0, stream>>>(V, ws);
    hh_apply<<<2048, 256, 0, stream>>>(X, V, ws, O);
}